// Round 1
// baseline (2177.701 us; speedup 1.0000x reference)
//
#include <hip/hip_runtime.h>

#define D     200
#define H     4
#define DH    50
#define NE    38
#define NTY   4
#define NC    608      // edge combos = 38*4*4
#define NCT   612      // + 4 self combos
#define BG    256      // graphs
#define LG    1024     // edges per graph
#define EE    262144   // E
#define NN    51200    // N
#define EA    313344   // E + N

// ---------------- histogram / combo ----------------
__global__ __launch_bounds__(256) void k_hist(const int* __restrict__ ei, const int* __restrict__ et,
                                              const int* __restrict__ nt, int* hist, int* outdeg,
                                              unsigned short* __restrict__ combo) {
    int e = blockIdx.x * 256 + threadIdx.x;
    if (e >= EE) return;
    int s = ei[e], d = ei[EE + e];
    int c = et[e] * 16 + nt[s] * 4 + nt[d];
    combo[e] = (unsigned short)c;
    atomicAdd(&hist[c], 1);
    atomicAdd(&outdeg[s], 1);
}

__global__ __launch_bounds__(256) void k_ntcnt(const int* __restrict__ nt, int* ntcnt) {
    int n = blockIdx.x * 256 + threadIdx.x;
    if (n < NN) atomicAdd(&ntcnt[nt[n]], 1);
}

__global__ void k_tcnt(const int* __restrict__ hist, int* tcnt) {
    int t = threadIdx.x;
    if (t < NE) { int s = 0; for (int i = 0; i < 16; i++) s += hist[t*16 + i]; tcnt[t] = s; }
}

// ---------------- sums of x_fact per edge type ----------------
__global__ __launch_bounds__(256) void k_xfsum(const int* __restrict__ ei, const int* __restrict__ et,
                                               const float* __restrict__ x, float* sums) {
    __shared__ float lds[NE * D];
    for (int i = threadIdx.x; i < NE * D; i += 256) lds[i] = 0.f;
    __syncthreads();
    int wave = threadIdx.x >> 6, lane = threadIdx.x & 63;
    int base = blockIdx.x * 512;
    for (int j = wave; j < 512; j += 4) {
        int e = base + j;
        int s = ei[e], d = ei[EE + e], t = et[e];
        const float* xs = x + (size_t)s * D;
        const float* xd = x + (size_t)d * D;
        float* row = lds + t * D;
        for (int dd = lane; dd < D; dd += 64)
            atomicAdd(&row[dd], xd[dd] - xs[dd]);
    }
    __syncthreads();
    for (int i = threadIdx.x; i < NE * D; i += 256) {
        float v = lds[i];
        if (v != 0.f) unsafeAtomicAdd(&sums[i], v);
    }
}

// ---------------- per-combo MLP pipeline ----------------
__global__ __launch_bounds__(256) void k_combos1(const float* __restrict__ We1, const float* __restrict__ be1,
                                                 const int* __restrict__ hist, const int* __restrict__ ntcnt,
                                                 float* __restrict__ h1, float* bn1) {
    int c = blockIdx.x, d = threadIdx.x;
    if (d >= D) return;
    float v, w;
    if (c < NC) {
        int etp = c >> 4, ts = (c >> 2) & 3, td = c & 3;
        v = We1[etp*D + d] + We1[(39+ts)*D + d] + We1[(43+td)*D + d] + be1[d];
        w = (float)hist[c];
    } else {
        int t = c - NC;
        v = We1[38*D + d] + We1[(39+t)*D + d] + We1[(43+t)*D + d] + be1[d];
        w = (float)ntcnt[t];
    }
    h1[c*D + d] = v;
    unsafeAtomicAdd(&bn1[d], w * v);
    unsafeAtomicAdd(&bn1[D + d], w * v * v);
}

__global__ __launch_bounds__(256) void k_combos2(const float* __restrict__ h1, const float* __restrict__ bn1,
                                                 const float* __restrict__ ge1, const float* __restrict__ bte1,
                                                 const float* __restrict__ We2, const float* __restrict__ be2,
                                                 float* __restrict__ embE, float* __restrict__ embS) {
    __shared__ float v[D];
    int c = blockIdx.x, t = threadIdx.x;
    if (t < D) {
        float cnt = (float)(EE + NN);
        float m = bn1[t] / cnt;
        float var = bn1[D + t] / cnt - m * m;
        float r = rsqrtf(var + 1e-5f);
        float u = (h1[c*D + t] - m) * r * ge1[t] + bte1[t];
        v[t] = fmaxf(u, 0.f);
    }
    __syncthreads();
    if (t < D) {
        float acc = be2[t];
        for (int k = 0; k < D; k++) acc += v[k] * We2[k*D + t];
        if (c < NC) embE[c*D + t] = acc; else embS[(c-NC)*D + t] = acc;
    }
}

__global__ __launch_bounds__(256) void k_combos3(const float* __restrict__ embE, const float* __restrict__ sumsxf,
                                                 const int* __restrict__ tcnt, const float* __restrict__ Wa1,
                                                 const float* __restrict__ ba1, const int* __restrict__ hist,
                                                 float* __restrict__ h2, float* bn2) {
    __shared__ float a[2*D];
    int c = blockIdx.x, t = threadIdx.x;
    int etp = c >> 4;
    if (t < D) {
        a[t] = embE[c*D + t];
        float cn = fmaxf((float)tcnt[etp], 1.f);
        a[D + t] = sumsxf[etp*D + t] / cn;
    }
    __syncthreads();
    if (t < D) {
        float acc = ba1[t];
        for (int k = 0; k < 2*D; k++) acc += a[k] * Wa1[k*D + t];
        h2[c*D + t] = acc;
        float w = (float)hist[c];
        unsafeAtomicAdd(&bn2[t], w * acc);
        unsafeAtomicAdd(&bn2[D + t], w * acc * acc);
    }
}

__global__ __launch_bounds__(256) void k_combos4(const float* __restrict__ h2, const float* __restrict__ bn2,
                                                 const float* __restrict__ ga1, const float* __restrict__ bta1,
                                                 const float* __restrict__ Wa2, const float* __restrict__ ba2,
                                                 float* __restrict__ Rc) {
    __shared__ float v[D];
    int c = blockIdx.x, t = threadIdx.x;
    if (t < D) {
        float inv = 1.f / (float)EE;
        float m = bn2[t] * inv;
        float var = bn2[D + t] * inv - m * m;
        float r = rsqrtf(var + 1e-5f);
        float u = (h2[c*D + t] - m) * r * ga1[t] + bta1[t];
        v[t] = fmaxf(u, 0.f);
    }
    __syncthreads();
    if (t < D) {
        float acc = ba2[t];
        for (int k = 0; k < D; k++) acc += v[k] * Wa2[k*D + t];
        Rc[c*D + t] = acc;
    }
}

// ---------------- per-graph attention over R ----------------
__global__ __launch_bounds__(256) void k_attn(const float* __restrict__ sent, const float* __restrict__ Watt,
                                              const float* __restrict__ Rc, const unsigned short* __restrict__ combo,
                                              float* __restrict__ upd) {
    __shared__ float q[D];
    __shared__ float sex[LG];
    __shared__ unsigned short cl[LG];
    __shared__ float red[8];
    int b = blockIdx.x, t = threadIdx.x;
    if (t < D) {
        float acc = 0.f;
        for (int k = 0; k < D; k++) acc += sent[b*D + k] * Watt[k*D + t];
        q[t] = acc;
    }
    for (int l = t; l < LG; l += 256) cl[l] = combo[b*LG + l];
    __syncthreads();
    int wave = t >> 6, lane = t & 63;
    const float scale = rsqrtf((float)D);
    for (int l = wave; l < LG; l += 4) {
        const float* r = Rc + cl[l] * D;
        float p = 0.f;
        for (int dd = lane; dd < D; dd += 64) p += q[dd] * r[dd];
        for (int o = 32; o; o >>= 1) p += __shfl_xor(p, o);
        if (lane == 0) sex[l] = p * scale;
    }
    __syncthreads();
    float mx = -1e30f;
    for (int l = t; l < LG; l += 256) mx = fmaxf(mx, sex[l]);
    for (int o = 32; o; o >>= 1) mx = fmaxf(mx, __shfl_xor(mx, o));
    if (lane == 0) red[wave] = mx;
    __syncthreads();
    mx = fmaxf(fmaxf(red[0], red[1]), fmaxf(red[2], red[3]));
    __syncthreads();
    float sm = 0.f;
    for (int l = t; l < LG; l += 256) { float e2 = expf(sex[l] - mx); sex[l] = e2; sm += e2; }
    for (int o = 32; o; o >>= 1) sm += __shfl_xor(sm, o);
    if (lane == 0) red[4 + wave] = sm;
    __syncthreads();
    float inv = 1.f / (red[4] + red[5] + red[6] + red[7]);
    if (t < D) {
        float acc = 0.f;
        for (int l = 0; l < LG; l++) acc += sex[l] * Rc[cl[l]*D + t];
        upd[b*D + t] = acc * inv;
    }
}

// ---------------- GK/GM (per graph) and SK/SM (per node type) ----------------
__global__ __launch_bounds__(256) void k_gkgm(const float* __restrict__ upd, const float* __restrict__ embS,
                                              const float* __restrict__ Wk, const float* __restrict__ bk,
                                              const float* __restrict__ Wm, const float* __restrict__ bm,
                                              float* GK, float* GM, float* SK, float* SM) {
    __shared__ float v[D];
    int bI = blockIdx.x, t = threadIdx.x;
    const float* in = (bI < BG) ? (upd + bI*D) : (embS + (bI - BG)*D);
    if (t < D) v[t] = in[t];
    __syncthreads();
    if (t < D) {
        float a1 = bk[t], a2 = bm[t];
        for (int k = 0; k < D; k++) {
            a1 += v[k] * Wk[(D + k)*D + t];
            a2 += v[k] * Wm[(D + k)*D + t];
        }
        if (bI < BG) { GK[bI*D + t] = a1; GM[bI*D + t] = a2; }
        else         { SK[(bI-BG)*D + t] = a1; SM[(bI-BG)*D + t] = a2; }
    }
}

// ---------------- generic NNx200 @ 200x200 matmul, 64-row tile, 8x8 micro ----------------
__global__ __launch_bounds__(256) void k_mm200(const float* __restrict__ A, const float* __restrict__ W,
                                               const float* __restrict__ bias, float* __restrict__ C,
                                               int preop, const float* __restrict__ bnacc, float invCnt,
                                               const float* __restrict__ g, const float* __restrict__ bb,
                                               float postscale) {
    __shared__ float aT[D * 68];      // aT[k*68 + r], 54.4 KB, 16B-aligned reads
    __shared__ float scl[D], sft[D];
    int t = threadIdx.x;
    int n0 = blockIdx.x * 64;
    if (preop) {
        if (t < D) {
            float m = bnacc[t] * invCnt;
            float var = bnacc[D + t] * invCnt - m * m;
            float rs = rsqrtf(var + 1e-5f);
            float s = rs * g[t];
            scl[t] = s;
            sft[t] = bb[t] - m * s;
        }
        __syncthreads();
    }
    for (int f = t; f < 64 * D; f += 256) {
        int r = f / D, k = f - r * D;
        float v = A[(size_t)(n0 + r) * D + k];
        if (preop) v = fmaxf(v * scl[k] + sft[k], 0.f);
        aT[k * 68 + r] = v;
    }
    __syncthreads();
    if (t < 200) {
        int rg = t / 25, cg = t - (t / 25) * 25;   // rg 0..7, cg 0..24
        int r0 = rg * 8, c0 = cg * 8;
        float acc[8][8];
        #pragma unroll
        for (int i = 0; i < 8; i++)
            #pragma unroll
            for (int j = 0; j < 8; j++) acc[i][j] = 0.f;
        for (int k = 0; k < D; k++) {
            const float4 a0 = *(const float4*)&aT[k * 68 + r0];
            const float4 a1 = *(const float4*)&aT[k * 68 + r0 + 4];
            const float4 w0 = *(const float4*)&W[k * D + c0];
            const float4 w1 = *(const float4*)&W[k * D + c0 + 4];
            float av[8] = {a0.x, a0.y, a0.z, a0.w, a1.x, a1.y, a1.z, a1.w};
            float wv[8] = {w0.x, w0.y, w0.z, w0.w, w1.x, w1.y, w1.z, w1.w};
            #pragma unroll
            for (int i = 0; i < 8; i++)
                #pragma unroll
                for (int j = 0; j < 8; j++) acc[i][j] += av[i] * wv[j];
        }
        float bj[8];
        #pragma unroll
        for (int j = 0; j < 8; j++) bj[j] = bias ? bias[c0 + j] : 0.f;
        #pragma unroll
        for (int i = 0; i < 8; i++) {
            size_t row = (size_t)(n0 + r0 + i);
            float4 o0, o1;
            o0.x = (acc[i][0] + bj[0]) * postscale;
            o0.y = (acc[i][1] + bj[1]) * postscale;
            o0.z = (acc[i][2] + bj[2]) * postscale;
            o0.w = (acc[i][3] + bj[3]) * postscale;
            o1.x = (acc[i][4] + bj[4]) * postscale;
            o1.y = (acc[i][5] + bj[5]) * postscale;
            o1.z = (acc[i][6] + bj[6]) * postscale;
            o1.w = (acc[i][7] + bj[7]) * postscale;
            *(float4*)&C[row * D + c0]     = o0;
            *(float4*)&C[row * D + c0 + 4] = o1;
        }
    }
}

// ---------------- attention scores (wave per entry) ----------------
__global__ __launch_bounds__(256) void k_sc(const int* __restrict__ ei, const int* __restrict__ nt,
                                            const float* __restrict__ XQ, const float* __restrict__ XK,
                                            const float* __restrict__ GK, const float* __restrict__ SK,
                                            float* __restrict__ sc, unsigned* smax) {
    int w = (blockIdx.x * 256 + threadIdx.x) >> 6;
    int lane = threadIdx.x & 63;
    if (w >= EA) return;
    int s, dno; const float* gk;
    if (w < EE) { s = ei[w]; dno = ei[EE + w]; gk = GK + (w >> 10) * D; }
    else        { s = w - EE; dno = s;         gk = SK + nt[s] * D; }
    const float* q  = XQ + (size_t)s * D;
    const float* kk = XK + (size_t)dno * D;
    float h0 = 0, h1 = 0, h2 = 0, h3 = 0;
    for (int dd = lane; dd < D; dd += 64) {
        float p = q[dd] * (kk[dd] + gk[dd]);
        int h = dd / DH;
        if (h == 0) h0 += p; else if (h == 1) h1 += p; else if (h == 2) h2 += p; else h3 += p;
    }
    for (int o = 32; o; o >>= 1) {
        h0 += __shfl_xor(h0, o); h1 += __shfl_xor(h1, o);
        h2 += __shfl_xor(h2, o); h3 += __shfl_xor(h3, o);
    }
    if (lane < 4) {
        float v = (lane == 0) ? h0 : (lane == 1) ? h1 : (lane == 2) ? h2 : h3;
        sc[w * 4 + lane] = v;
        unsigned enc = __float_as_uint(v);
        enc = (enc & 0x80000000u) ? ~enc : (enc | 0x80000000u);
        atomicMax(&smax[s * 4 + lane], enc);
    }
}

__global__ __launch_bounds__(256) void k_exden(const int* __restrict__ ei, float* __restrict__ sc,
                                               const unsigned* __restrict__ smax, float* den) {
    int i = blockIdx.x * 256 + threadIdx.x;
    if (i >= EA * 4) return;
    int w = i >> 2, h = i & 3;
    int s = (w < EE) ? ei[w] : (w - EE);
    unsigned enc = smax[s * 4 + h];
    unsigned u = (enc & 0x80000000u) ? (enc ^ 0x80000000u) : ~enc;
    float m = __uint_as_float(u);
    float e2 = expf(sc[i] - m);
    sc[i] = e2;
    unsafeAtomicAdd(&den[s * 4 + h], e2);
}

__global__ __launch_bounds__(256) void k_msg(const int* __restrict__ ei, const int* __restrict__ nt,
                                             const float* __restrict__ sc, const float* __restrict__ den,
                                             const int* __restrict__ outdeg, const float* __restrict__ XM,
                                             const float* __restrict__ GM, const float* __restrict__ SM,
                                             float* aggr) {
    int w = (blockIdx.x * 256 + threadIdx.x) >> 6;
    int lane = threadIdx.x & 63;
    if (w >= EA) return;
    int s, dno; const float* gm;
    if (w < EE) { s = ei[w]; dno = ei[EE + w]; gm = GM + (w >> 10) * D; }
    else        { s = w - EE; dno = s;         gm = SM + nt[s] * D; }
    float cnt = (float)(outdeg[s] + 1);
    float alpha[4];
    #pragma unroll
    for (int h = 0; h < 4; h++) alpha[h] = sc[w * 4 + h] / den[s * 4 + h] * cnt;
    const float* xm = XM + (size_t)s * D;
    for (int dd = lane; dd < D; dd += 64) {
        float v = (xm[dd] + gm[dd]) * alpha[dd / DH];
        unsafeAtomicAdd(&aggr[(size_t)dno * D + dd], v);
    }
}

// ---------------- column stats for final BN ----------------
__global__ __launch_bounds__(256) void k_colstats(const float* __restrict__ T1, float* bn3) {
    int t = threadIdx.x;
    if (t >= D) return;
    int r0 = blockIdx.x * 256;
    float s = 0.f, q = 0.f;
    for (int r = r0; r < r0 + 256; r++) {
        float v = T1[(size_t)r * D + t];
        s += v; q += v * v;
    }
    unsafeAtomicAdd(&bn3[t], s);
    unsafeAtomicAdd(&bn3[D + t], q);
}

extern "C" void kernel_launch(void* const* d_in, const int* in_sizes, int n_in,
                              void* d_out, int out_size, void* d_ws, size_t ws_size,
                              hipStream_t stream) {
    const float* x    = (const float*)d_in[0];
    const float* sent = (const float*)d_in[2];
    const float* We1  = (const float*)d_in[3];
    const float* be1  = (const float*)d_in[4];
    const float* ge1  = (const float*)d_in[5];
    const float* bte1 = (const float*)d_in[6];
    const float* We2  = (const float*)d_in[7];
    const float* be2  = (const float*)d_in[8];
    const float* Wa1  = (const float*)d_in[9];
    const float* ba1  = (const float*)d_in[10];
    const float* ga1  = (const float*)d_in[11];
    const float* bta1 = (const float*)d_in[12];
    const float* Wa2  = (const float*)d_in[13];
    const float* ba2  = (const float*)d_in[14];
    const float* Watt = (const float*)d_in[15];
    const float* Wk   = (const float*)d_in[16];
    const float* bk   = (const float*)d_in[17];
    const float* Wm   = (const float*)d_in[18];
    const float* bm   = (const float*)d_in[19];
    const float* Wq   = (const float*)d_in[20];
    const float* bq   = (const float*)d_in[21];
    const float* Wo1  = (const float*)d_in[22];
    const float* bo1  = (const float*)d_in[23];
    const float* go1  = (const float*)d_in[24];
    const float* bto1 = (const float*)d_in[25];
    const float* Wo2  = (const float*)d_in[26];
    const float* bo2  = (const float*)d_in[27];
    const int* ei = (const int*)d_in[28];
    const int* et = (const int*)d_in[29];
    const int* nt = (const int*)d_in[30];

    char* ws = (char*)d_ws;
    size_t off = 0;
    auto alloc = [&](size_t bytes) -> char* {
        char* p = ws + off;
        off = (off + bytes + 255) & ~(size_t)255;
        return p;
    };
    int*      hist   = (int*)     alloc(NC * 4);
    int*      ntcnt  = (int*)     alloc(NTY * 4);
    int*      tcnt   = (int*)     alloc(NE * 4);
    float*    bn1    = (float*)   alloc(2 * D * 4);
    float*    bn2    = (float*)   alloc(2 * D * 4);
    float*    bn3    = (float*)   alloc(2 * D * 4);
    float*    sumsxf = (float*)   alloc(NE * D * 4);
    int*      outdeg = (int*)     alloc(NN * 4);
    float*    den    = (float*)   alloc((size_t)NN * H * 4);
    unsigned* smax   = (unsigned*)alloc((size_t)NN * H * 4);   // 0 == -inf sentinel (encoded)
    size_t zero_end = off;
    unsigned short* combo = (unsigned short*)alloc((size_t)EE * 2);
    float* h1v   = (float*)alloc((size_t)NCT * D * 4);
    float* embE  = (float*)alloc((size_t)NC * D * 4);
    float* embS  = (float*)alloc((size_t)NTY * D * 4);
    float* h2pre = (float*)alloc((size_t)NC * D * 4);
    float* Rc    = (float*)alloc((size_t)NC * D * 4);
    float* upd   = (float*)alloc((size_t)BG * D * 4);
    float* GK    = (float*)alloc((size_t)BG * D * 4);
    float* GM    = (float*)alloc((size_t)BG * D * 4);
    float* SK    = (float*)alloc((size_t)NTY * D * 4);
    float* SM    = (float*)alloc((size_t)NTY * D * 4);
    float* sc    = (float*)alloc((size_t)EA * H * 4);
    float* XK    = (float*)alloc((size_t)NN * D * 4);
    float* XM    = (float*)alloc((size_t)NN * D * 4);
    float* XQ    = (float*)alloc((size_t)NN * D * 4);
    float* aggr = XK;   // XK dead after k_sc
    float* T1   = XQ;   // XQ dead after k_sc

    hipMemsetAsync(ws, 0, zero_end, stream);

    k_hist  <<<EE / 256, 256, 0, stream>>>(ei, et, nt, hist, outdeg, combo);
    k_ntcnt <<<NN / 256, 256, 0, stream>>>(nt, ntcnt);
    k_xfsum <<<512, 256, 0, stream>>>(ei, et, x, sumsxf);
    k_tcnt  <<<1, 64, 0, stream>>>(hist, tcnt);
    k_combos1<<<NCT, 256, 0, stream>>>(We1, be1, hist, ntcnt, h1v, bn1);
    k_combos2<<<NCT, 256, 0, stream>>>(h1v, bn1, ge1, bte1, We2, be2, embE, embS);
    k_combos3<<<NC, 256, 0, stream>>>(embE, sumsxf, tcnt, Wa1, ba1, hist, h2pre, bn2);
    k_combos4<<<NC, 256, 0, stream>>>(h2pre, bn2, ga1, bta1, Wa2, ba2, Rc);
    k_attn  <<<BG, 256, 0, stream>>>(sent, Watt, Rc, combo, upd);
    k_gkgm  <<<BG + NTY, 256, 0, stream>>>(upd, embS, Wk, bk, Wm, bm, GK, GM, SK, SM);
    k_mm200 <<<NN / 64, 256, 0, stream>>>(x, Wk, nullptr, XK, 0, nullptr, 0.f, nullptr, nullptr, 1.f);
    k_mm200 <<<NN / 64, 256, 0, stream>>>(x, Wm, nullptr, XM, 0, nullptr, 0.f, nullptr, nullptr, 1.f);
    k_mm200 <<<NN / 64, 256, 0, stream>>>(x, Wq, bq, XQ, 0, nullptr, 0.f, nullptr, nullptr, 0.14142135623730950488f);
    k_sc    <<<EA / 4, 256, 0, stream>>>(ei, nt, XQ, XK, GK, SK, sc, smax);
    hipMemsetAsync(aggr, 0, (size_t)NN * D * 4, stream);
    k_exden <<<(EA * 4) / 256, 256, 0, stream>>>(ei, sc, smax, den);
    k_msg   <<<EA / 4, 256, 0, stream>>>(ei, nt, sc, den, outdeg, XM, GM, SM, aggr);
    k_mm200 <<<NN / 64, 256, 0, stream>>>(aggr, Wo1, bo1, T1, 0, nullptr, 0.f, nullptr, nullptr, 1.f);
    k_colstats<<<NN / 256, 256, 0, stream>>>(T1, bn3);
    k_mm200 <<<NN / 64, 256, 0, stream>>>(T1, Wo2, bo2, (float*)d_out, 1, bn3, 1.f / (float)NN, go1, bto1, 1.f);
}